// Round 9
// baseline (461.807 us; speedup 1.0000x reference)
//
#include <hip/hip_runtime.h>
#include <math.h>

// ---------------------------------------------------------------------------
// B=4096. conv1 (64,5,7) pad3 + relu + pool4 -> h1 (64,96)
//         conv2 (128,64,5) pad2 + relu + pool4 -> feat (128,24)
//         fc: only cols 0..5 of (404,3072) + tau = feat·(L_w@fc_w) + const.
// Precision: conv1 = 3-term split-bf16 (err ~2^-16/prod). conv2 = 2-term
// fp16: A = h1 single fp16 (one LDS array), B = 1024*w2 split fp16 hi/lo
// (scale keeps lo normal; epilogue *2^-10). err ~2^-12/prod — fits the
// 460.8 threshold with ~2x margin (measured 16 at 2^-16).
// Both convs on v_mfma_f32_32x32x16_{bf16,f16}.
// C/D (m74/m101): col=lane&31(oc), row=(reg&3)+8*(reg>>2)+4*(lane>>5) ->
// reg-quads = 4 consecutive pos -> pool4 in-register.
// LDS 22.4 KB -> 7 blocks/CU (was 4).
// ---------------------------------------------------------------------------

typedef short bf16x8 __attribute__((ext_vector_type(8)));
typedef _Float16 f16x8 __attribute__((ext_vector_type(8)));
typedef float f32x4  __attribute__((ext_vector_type(4)));
typedef float f32x16 __attribute__((ext_vector_type(16)));
typedef int   i32x4  __attribute__((ext_vector_type(4)));

union Frag { int u[4]; i32x4 q; bf16x8 v; f16x8 h; };
union H16 { _Float16 hf; unsigned short us; };

__device__ __forceinline__ unsigned bf16_rne(float f) {
    unsigned u = __float_as_uint(f);
    return (u + 0x7fffu + ((u >> 16) & 1u)) >> 16;
}
__device__ __forceinline__ unsigned packsplit(float f) {
    unsigned hi = bf16_rne(f);
    float lo = f - __uint_as_float(hi << 16);
    return (hi << 16) | bf16_rne(lo);
}
__device__ __forceinline__ unsigned short f16_rne(float f) {
    H16 c; c.hf = (_Float16)f; return c.us;
}

#define ZERO16 {0.f,0.f,0.f,0.f,0.f,0.f,0.f,0.f,0.f,0.f,0.f,0.f,0.f,0.f,0.f,0.f}

// ---------------------------------------------------------------------------
// Kernel 0 (merged): fc7 (blocks 0..47), taub+wfrag1 (48), wfrag2 (49..68).
//  wfrag1: [ks3][nt2][lane64][part2][4u32] bf16 split; k'=ks*16+(lane>>5)*8+j,
//          ic=k'>>3, dk=k'&7 (ic==5 -> zero)
//  wfrag2: [step20][nt4][lane64][part2][4u32] fp16 of 1024*w2; part0=hi,
//          part1=lo; step=dk*4+icc; k_ic=icc*16+(lane>>5)*8+j
// ---------------------------------------------------------------------------
__global__ void precompute_kernel(const float* __restrict__ w1,
                                  const float* __restrict__ w2,
                                  const float* __restrict__ fc_w,
                                  const float* __restrict__ fc_b,
                                  const float* __restrict__ L_w,
                                  const float* __restrict__ L_b,
                                  float* __restrict__ fc7,
                                  float* __restrict__ taub,
                                  unsigned* __restrict__ wfrag1,
                                  unsigned* __restrict__ wfrag2) {
    const int t = threadIdx.x, bb = blockIdx.x;
    if (bb < 48) {
        __shared__ float part[3][64];
        const int k = bb * 64 + (t & 63), jc = t >> 6;
        const int j0 = jc * 101;
        float s = 0.f;
        #pragma unroll 4
        for (int j = j0; j < j0 + 101; ++j) s += L_w[j] * fc_w[j * 3072 + k];
        if (jc) part[jc - 1][t & 63] = s;
        __syncthreads();
        if (jc == 0) {
            const int kk = t & 63;
            float r[8];
            #pragma unroll
            for (int j = 0; j < 6; ++j) r[j] = fc_w[j * 3072 + k];
            r[6] = s + part[0][kk] + part[1][kk] + part[2][kk];
            r[7] = 0.f;
            #pragma unroll
            for (int j = 0; j < 8; ++j) fc7[k * 8 + j] = r[j];
        }
    } else if (bb == 48) {
        if (t < 64) {
            float s = 0.f;
            for (int j = t; j < 404; j += 64) s += L_w[j] * fc_b[j];
            #pragma unroll
            for (int off = 32; off; off >>= 1) s += __shfl_down(s, off);
            if (t == 0) taub[0] = s + L_b[0];
        }
        for (int i = t; i < 768; i += 256) {        // conv1 frags (bf16 split)
            const int part = i & 1, lane = (i >> 1) & 63,
                      nt = (i >> 7) & 1, ks = i >> 8;        // 0..2
            const int oc = nt * 32 + (lane & 31);
            unsigned h[8];
            #pragma unroll
            for (int j = 0; j < 8; ++j) {
                const int kp = ks * 16 + (lane >> 5) * 8 + j;  // k' = ic*8+dk
                const int ic = kp >> 3, dk = kp & 7;
                float v = (ic < 5 && dk < 7) ? w1[oc * 35 + ic * 7 + dk] : 0.f;
                unsigned hb = bf16_rne(v);
                if (part) hb = bf16_rne(v - __uint_as_float(hb << 16));
                h[j] = hb;
            }
            #pragma unroll
            for (int wj = 0; wj < 4; ++wj)
                wfrag1[i * 4 + wj] = (h[2 * wj + 1] << 16) | h[2 * wj];
        }
    } else {                                        // conv2 frags (fp16 x1024)
        const int base = (bb - 49) * 512;
        #pragma unroll
        for (int r = 0; r < 2; ++r) {
            const int i = base + r * 256 + t;
            const int part = i & 1, lane = (i >> 1) & 63,
                      nt = (i >> 7) & 3, step = i >> 9;       // 0..19
            const int oc = nt * 32 + (lane & 31);
            const int dk = step >> 2, icc = step & 3;
            unsigned short h[8];
            #pragma unroll
            for (int j = 0; j < 8; ++j) {
                const int ic = icc * 16 + (lane >> 5) * 8 + j;  // k = ic
                const float v = w2[oc * 320 + ic * 5 + dk] * 1024.0f;
                H16 c; c.hf = (_Float16)v;
                if (part) { const float rr = v - (float)c.hf; c.hf = (_Float16)rr; }
                h[j] = c.us;
            }
            #pragma unroll
            for (int wj = 0; wj < 4; ++wj)
                wfrag2[i * 4 + wj] = ((unsigned)h[2 * wj + 1] << 16) | h[2 * wj];
        }
    }
}

// ---------------------------------------------------------------------------
// Kernel 1: fused conv1+conv2+fc, one batch per block, 7 blocks/CU.
// LDS (22368 B): lds_in u32[5][392] packed bf16 hi|lo (halo cols zero),
//   h1f fp16[100][72] (rows 0,1,98,99 halo-zero), red f32[32].
// ---------------------------------------------------------------------------
__global__ __launch_bounds__(256, 7) void fused_kernel(
    const float* __restrict__ input,
    const float* __restrict__ b1,
    const float* __restrict__ b2,
    const unsigned* __restrict__ wfrag1,
    const unsigned* __restrict__ wfrag2,
    const float* __restrict__ fc7,
    const float* __restrict__ fc_b,
    const float* __restrict__ taubp,
    float* __restrict__ params)
{
    __shared__ unsigned lds_in[1960];                       // [5][392]
    __shared__ __align__(16) unsigned short h1f[7200];      // [100][72]
    __shared__ float red[32];

    const int t = threadIdx.x, b = blockIdx.x;
    const int lane = t & 63, w = t >> 6;
    const int lq = lane & 31, hi = lane >> 5;

    // ---- zero lds_in + h1 halo rows (0,1,98,99) ----
    for (int i = t; i < 1960; i += 256) lds_in[i] = 0u;
    if (t < 144) {
        const int r = t / 36, wd = t - r * 36;
        const int row = (r < 2) ? r : 96 + r;
        ((unsigned*)h1f)[row * 36 + wd] = 0u;
    }
    __syncthreads();
    const float* inb = input + (size_t)b * 1920;
    for (int i = t; i < 1920; i += 256) {
        const int ic = i / 384, x = i - ic * 384;
        lds_in[ic * 392 + 3 + x] = packsplit(inb[i]);
    }
    __syncthreads();

    // ------------- conv1: C[pos=384][oc=64], K'=48 (3 ks of 16) -------------
    // wave w owns mtiles w*3..w*3+2 (32 pos each), both oc-ntiles.
    const i32x4* w1f = (const i32x4*)wfrag1;
    Frag c1b[3][2][2];                       // [ks][nt][part]
    #pragma unroll
    for (int ks = 0; ks < 3; ++ks)
        #pragma unroll
        for (int nt = 0; nt < 2; ++nt) {
            const int fi = ((ks * 2 + nt) * 64 + lane) * 2;
            c1b[ks][nt][0].q = w1f[fi];
            c1b[ks][nt][1].q = w1f[fi + 1];
        }
    float b1v[2];
    #pragma unroll
    for (int nt = 0; nt < 2; ++nt) b1v[nt] = b1[nt * 32 + lq];

    #pragma unroll
    for (int m = 0; m < 3; ++m) {
        const int mtile = w * 3 + m;
        f32x16 acc0 = ZERO16, acc1 = ZERO16;
        #pragma unroll
        for (int ks = 0; ks < 3; ++ks) {
            // ic = ks*2+hi; ks==2,hi==1 -> ic=5 (virtual zero row): clamp+mask
            const int rowoff = (ks == 2) ? 4 * 392 : (ks * 2 + hi) * 392;
            const unsigned* src = lds_in + rowoff + mtile * 32 + lq;
            unsigned p[8];
            #pragma unroll
            for (int j = 0; j < 8; ++j) p[j] = src[j];
            Frag ah, al;
            #pragma unroll
            for (int wj = 0; wj < 4; ++wj) {
                ah.u[wj] = __builtin_amdgcn_perm(p[2*wj+1], p[2*wj], 0x07060302u);
                al.u[wj] = __builtin_amdgcn_perm(p[2*wj+1], p[2*wj], 0x05040100u);
            }
            if (ks == 2) {
                #pragma unroll
                for (int wj = 0; wj < 4; ++wj) {
                    ah.u[wj] = hi ? 0 : ah.u[wj];
                    al.u[wj] = hi ? 0 : al.u[wj];
                }
            }
            acc0 = __builtin_amdgcn_mfma_f32_32x32x16_bf16(ah.v, c1b[ks][0][0].v, acc0, 0, 0, 0);
            acc1 = __builtin_amdgcn_mfma_f32_32x32x16_bf16(ah.v, c1b[ks][1][0].v, acc1, 0, 0, 0);
            acc0 = __builtin_amdgcn_mfma_f32_32x32x16_bf16(ah.v, c1b[ks][0][1].v, acc0, 0, 0, 0);
            acc1 = __builtin_amdgcn_mfma_f32_32x32x16_bf16(ah.v, c1b[ks][1][1].v, acc1, 0, 0, 0);
            acc0 = __builtin_amdgcn_mfma_f32_32x32x16_bf16(al.v, c1b[ks][0][0].v, acc0, 0, 0, 0);
            acc1 = __builtin_amdgcn_mfma_f32_32x32x16_bf16(al.v, c1b[ks][1][0].v, acc1, 0, 0, 0);
        }
        // pool4 + relu + single-fp16 write: reg-quad q = rows 8q+4hi+0..3
        #pragma unroll
        for (int q = 0; q < 4; ++q) {
            const int c = mtile * 8 + 2 * q + hi;
            {
                float s = 0.f;
                #pragma unroll
                for (int r4 = 0; r4 < 4; ++r4) s += fmaxf(acc0[q*4+r4] + b1v[0], 0.f);
                h1f[(c + 2) * 72 + lq] = f16_rne(0.25f * s);
            }
            {
                float s = 0.f;
                #pragma unroll
                for (int r4 = 0; r4 < 4; ++r4) s += fmaxf(acc1[q*4+r4] + b1v[1], 0.f);
                h1f[(c + 2) * 72 + 32 + lq] = f16_rne(0.25f * s);
            }
        }
    }
    __syncthreads();

    // ------ conv2: 20 k-steps (dk*4+icc), wave = ntile w, mtiles 0..2 ------
    // A = h1 fp16 single; B = 1024*w2 split fp16 (bh,bl); 2 MFMA per (s,mt).
    f32x16 acc2[3] = {ZERO16, ZERO16, ZERO16};

    const i32x4* aF = (const i32x4*)(h1f + lq * 72 + hi * 8);
    const i32x4* w2f = (const i32x4*)wfrag2;
    Frag b2h[2], b2l[2];                     // B double-buffer
    Frag a2[2];                              // A rolling buffer

    {   // prologue: B(step0), A(step0, mt0)
        const int fi = (w * 64 + lane) * 2;
        b2h[0].q = w2f[fi];
        b2l[0].q = w2f[fi + 1];
        a2[0].q = aF[0];
    }

    #pragma unroll
    for (int s = 0; s < 20; ++s) {
        const int sb = s & 1, snb = sb ^ 1;
        if (s < 19) {
            const int fi = (((s + 1) * 4 + w) * 64 + lane) * 2;
            b2h[snb].q = w2f[fi];
            b2l[snb].q = w2f[fi + 1];
        }
        #pragma unroll
        for (int mt = 0; mt < 3; ++mt) {
            const int it = s * 3 + mt, cur = it & 1, nxt = cur ^ 1;
            if (it < 59) {
                const int nit = it + 1, nmt = nit % 3, ns = nit / 3;
                const int off = (nmt * 32 + (ns >> 2)) * 9 + (ns & 3) * 2;
                a2[nxt].q = aF[off];
            }
            acc2[mt] = __builtin_amdgcn_mfma_f32_32x32x16_f16(a2[cur].h, b2h[sb].h, acc2[mt], 0, 0, 0);
            acc2[mt] = __builtin_amdgcn_mfma_f32_32x32x16_f16(a2[cur].h, b2l[sb].h, acc2[mt], 0, 0, 0);
        }
    }

    // ---- epilogue: unscale (2^-10) + bias + relu + pool4 -> feat; fc7 ----
    float dot[7] = {0.f, 0.f, 0.f, 0.f, 0.f, 0.f, 0.f};
    {
        const float b2v = b2[w * 32 + lq];
        #pragma unroll
        for (int mt = 0; mt < 3; ++mt) {
            #pragma unroll
            for (int q = 0; q < 4; ++q) {
                float s = 0.f;
                #pragma unroll
                for (int r4 = 0; r4 < 4; ++r4)
                    s += fmaxf(acc2[mt][q*4+r4] * 0.0009765625f + b2v, 0.f);
                s *= 0.25f;
                const int fq = mt * 8 + 2 * q + hi;
                const int idx = (w * 32 + lq) * 24 + fq;
                const f32x4* fp = (const f32x4*)(fc7 + idx * 8);
                const f32x4 f0 = fp[0], f1 = fp[1];
                dot[0] += s * f0[0]; dot[1] += s * f0[1];
                dot[2] += s * f0[2]; dot[3] += s * f0[3];
                dot[4] += s * f1[0]; dot[5] += s * f1[1];
                dot[6] += s * f1[2];
            }
        }
    }

    #pragma unroll
    for (int j = 0; j < 7; ++j) {
        float s = dot[j];
        #pragma unroll
        for (int off = 32; off; off >>= 1) s += __shfl_down(s, off);
        if (lane == 0) red[w * 8 + j] = s;
    }
    __syncthreads();
    if (t < 7) {
        float s = red[t] + red[8 + t] + red[16 + t] + red[24 + t];
        s += (t < 6) ? fc_b[t] : taubp[0];
        params[(size_t)b * 8 + t] = s;
    }
}

// ---------------------------------------------------------------------------
// Kernel 2: DMP rollout — 1 thread per batch element.
// ---------------------------------------------------------------------------
__global__ void rollout_kernel(const float* __restrict__ params,
                               const float* __restrict__ y0,
                               float* __restrict__ out) {
    const int b = blockIdx.x * 256 + threadIdx.x;
    const float* p = params + (size_t)b * 8;
    const float goal = p[0];
    const float w0 = p[1], w1 = p[2], w2 = p[3], w3 = p[4], w4 = p[5];
    const float tau = p[6];
    const float y0v = y0[b];

    const float c0 = 1.0f;
    const float c1 = 0.77880078307140486825f;
    const float c2 = 0.60653065971263342360f;
    const float c3 = 0.47236655274101470714f;
    const float c4 = 0.36787944117144232160f;
    const float inv2s = -0.5f / 11.180339887498949f;
    const float e0 = inv2s * c0, e1 = inv2s * c1, e2 = inv2s * c2,
                e3 = inv2s * c3, e4 = inv2s * c4;

    float x = 1.0f, y = y0v, z = 0.01f * tau;
    const float td = tau * 0.01f;
    const float gmy0 = goal - y0v;
    float* ob = out + (size_t)b * 101;
    ob[0] = y0v;
    for (int s = 1; s <= 100; ++s) {
        x = x - x * td;
        const float d0 = x - c0, d1 = x - c1, d2 = x - c2, d3 = x - c3, d4 = x - c4;
        const float p0 = __expf(e0 * d0 * d0);
        const float p1 = __expf(e1 * d1 * d1);
        const float p2 = __expf(e2 * d2 * d2);
        const float p3 = __expf(e3 * d3 * d3);
        const float p4 = __expf(e4 * d4 * d4);
        const float den = p0 + p1 + p2 + p3 + p4;
        const float num = w0 * p0 + w1 * p1 + w2 * p2 + w3 * p3 + w4 * p4;
        const float fx = (num / den) * x * gmy0;
        const float dz = 25.0f * (6.25f * (goal - y) - z) + fx;
        const float dy = z;
        y += dy * td;
        z += dz * td;
        ob[s] = y;
    }
}

extern "C" void kernel_launch(void* const* d_in, const int* in_sizes, int n_in,
                              void* d_out, int out_size, void* d_ws, size_t ws_size,
                              hipStream_t stream) {
    const float* input = (const float*)d_in[0];
    const float* y0    = (const float*)d_in[1];
    const float* w1    = (const float*)d_in[2];
    const float* b1    = (const float*)d_in[3];
    const float* w2    = (const float*)d_in[4];
    const float* b2    = (const float*)d_in[5];
    const float* fc_w  = (const float*)d_in[6];
    const float* fc_b  = (const float*)d_in[7];
    const float* L_w   = (const float*)d_in[8];
    const float* L_b   = (const float*)d_in[9];
    float* out = (float*)d_out;

    float* ws      = (float*)d_ws;
    float* fc7     = ws;                          // 24576 f
    float* taub    = ws + 24576;                  // pad to 64
    float* params  = ws + 24640;                  // 32768 f
    unsigned* wfrag1 = (unsigned*)(ws + 57408);   // 3072 u32 (pad to 4096)
    unsigned* wfrag2 = wfrag1 + 4096;             // 40960 u32

    const int B = in_sizes[1];                    // 4096

    precompute_kernel<<<69, 256, 0, stream>>>(w1, w2, fc_w, fc_b, L_w, L_b,
                                              fc7, taub, wfrag1, wfrag2);
    fused_kernel<<<B, 256, 0, stream>>>(input, b1, b2, wfrag1, wfrag2,
                                        fc7, fc_b, taub, params);
    rollout_kernel<<<B / 256, 256, 0, stream>>>(params, y0, out);
}

// Round 10
// 140.452 us; speedup vs baseline: 3.2880x; 3.2880x over previous
//
#include <hip/hip_runtime.h>
#include <math.h>

// ---------------------------------------------------------------------------
// B=4096. conv1 (64,5,7) pad3 + relu + pool4 -> h1 (64,96)
//         conv2 (128,64,5) pad2 + relu + pool4 -> feat (128,24)
//         fc: only cols 0..5 of (404,3072) + tau = feat·(L_w@fc_w) + const.
// Precision: conv1 = 3-term split-bf16 (err ~2^-16/prod). conv2 = 2-term
// fp16: A = h1 single fp16, B = 1024*w2 split fp16 hi/lo (scale keeps lo
// normal; epilogue *2^-10). Measured absmax 64 vs threshold 460.8.
// Both convs on v_mfma_f32_32x32x16_{bf16,f16}.
// C/D (m74/m101): col=lane&31(oc), row=(reg&3)+8*(reg>>2)+4*(lane>>5) ->
// reg-quads = 4 consecutive pos -> pool4 in-register.
// R10: launch_bounds (256,4) — R9's (256,7) capped regs at ~73 < the ~104
// needed (48 AGPR acc) -> accumulator spill, 1.7 GB scratch traffic, 4x slow.
// ---------------------------------------------------------------------------

typedef short bf16x8 __attribute__((ext_vector_type(8)));
typedef _Float16 f16x8 __attribute__((ext_vector_type(8)));
typedef float f32x4  __attribute__((ext_vector_type(4)));
typedef float f32x16 __attribute__((ext_vector_type(16)));
typedef int   i32x4  __attribute__((ext_vector_type(4)));

union Frag { int u[4]; i32x4 q; bf16x8 v; f16x8 h; };
union H16 { _Float16 hf; unsigned short us; };

__device__ __forceinline__ unsigned bf16_rne(float f) {
    unsigned u = __float_as_uint(f);
    return (u + 0x7fffu + ((u >> 16) & 1u)) >> 16;
}
__device__ __forceinline__ unsigned packsplit(float f) {
    unsigned hi = bf16_rne(f);
    float lo = f - __uint_as_float(hi << 16);
    return (hi << 16) | bf16_rne(lo);
}
__device__ __forceinline__ unsigned short f16_rne(float f) {
    H16 c; c.hf = (_Float16)f; return c.us;
}

#define ZERO16 {0.f,0.f,0.f,0.f,0.f,0.f,0.f,0.f,0.f,0.f,0.f,0.f,0.f,0.f,0.f,0.f}

// ---------------------------------------------------------------------------
// Kernel 0 (merged): fc7 (blocks 0..47), taub+wfrag1 (48), wfrag2 (49..68).
//  wfrag1: [ks3][nt2][lane64][part2][4u32] bf16 split; k'=ks*16+(lane>>5)*8+j,
//          ic=k'>>3, dk=k'&7 (ic==5 -> zero)
//  wfrag2: [step20][nt4][lane64][part2][4u32] fp16 of 1024*w2; part0=hi,
//          part1=lo; step=dk*4+icc; k_ic=icc*16+(lane>>5)*8+j
// ---------------------------------------------------------------------------
__global__ void precompute_kernel(const float* __restrict__ w1,
                                  const float* __restrict__ w2,
                                  const float* __restrict__ fc_w,
                                  const float* __restrict__ fc_b,
                                  const float* __restrict__ L_w,
                                  const float* __restrict__ L_b,
                                  float* __restrict__ fc7,
                                  float* __restrict__ taub,
                                  unsigned* __restrict__ wfrag1,
                                  unsigned* __restrict__ wfrag2) {
    const int t = threadIdx.x, bb = blockIdx.x;
    if (bb < 48) {
        __shared__ float part[3][64];
        const int k = bb * 64 + (t & 63), jc = t >> 6;
        const int j0 = jc * 101;
        float s = 0.f;
        #pragma unroll 4
        for (int j = j0; j < j0 + 101; ++j) s += L_w[j] * fc_w[j * 3072 + k];
        if (jc) part[jc - 1][t & 63] = s;
        __syncthreads();
        if (jc == 0) {
            const int kk = t & 63;
            float r[8];
            #pragma unroll
            for (int j = 0; j < 6; ++j) r[j] = fc_w[j * 3072 + k];
            r[6] = s + part[0][kk] + part[1][kk] + part[2][kk];
            r[7] = 0.f;
            #pragma unroll
            for (int j = 0; j < 8; ++j) fc7[k * 8 + j] = r[j];
        }
    } else if (bb == 48) {
        if (t < 64) {
            float s = 0.f;
            for (int j = t; j < 404; j += 64) s += L_w[j] * fc_b[j];
            #pragma unroll
            for (int off = 32; off; off >>= 1) s += __shfl_down(s, off);
            if (t == 0) taub[0] = s + L_b[0];
        }
        for (int i = t; i < 768; i += 256) {        // conv1 frags (bf16 split)
            const int part = i & 1, lane = (i >> 1) & 63,
                      nt = (i >> 7) & 1, ks = i >> 8;        // 0..2
            const int oc = nt * 32 + (lane & 31);
            unsigned h[8];
            #pragma unroll
            for (int j = 0; j < 8; ++j) {
                const int kp = ks * 16 + (lane >> 5) * 8 + j;  // k' = ic*8+dk
                const int ic = kp >> 3, dk = kp & 7;
                float v = (ic < 5 && dk < 7) ? w1[oc * 35 + ic * 7 + dk] : 0.f;
                unsigned hb = bf16_rne(v);
                if (part) hb = bf16_rne(v - __uint_as_float(hb << 16));
                h[j] = hb;
            }
            #pragma unroll
            for (int wj = 0; wj < 4; ++wj)
                wfrag1[i * 4 + wj] = (h[2 * wj + 1] << 16) | h[2 * wj];
        }
    } else {                                        // conv2 frags (fp16 x1024)
        const int base = (bb - 49) * 512;
        #pragma unroll
        for (int r = 0; r < 2; ++r) {
            const int i = base + r * 256 + t;
            const int part = i & 1, lane = (i >> 1) & 63,
                      nt = (i >> 7) & 3, step = i >> 9;       // 0..19
            const int oc = nt * 32 + (lane & 31);
            const int dk = step >> 2, icc = step & 3;
            unsigned short h[8];
            #pragma unroll
            for (int j = 0; j < 8; ++j) {
                const int ic = icc * 16 + (lane >> 5) * 8 + j;  // k = ic
                const float v = w2[oc * 320 + ic * 5 + dk] * 1024.0f;
                H16 c; c.hf = (_Float16)v;
                if (part) { const float rr = v - (float)c.hf; c.hf = (_Float16)rr; }
                h[j] = c.us;
            }
            #pragma unroll
            for (int wj = 0; wj < 4; ++wj)
                wfrag2[i * 4 + wj] = ((unsigned)h[2 * wj + 1] << 16) | h[2 * wj];
        }
    }
}

// ---------------------------------------------------------------------------
// Kernel 1: fused conv1+conv2+fc, one batch per block.
// LDS (22368 B): lds_in u32[5][392] packed bf16 hi|lo (halo cols zero),
//   h1f fp16[100][72] (rows 0,1,98,99 halo-zero), red f32[32].
// Regs: ~104 peak (48 AGPR acc + ~56 VGPR) -> (256,4), NO spill.
// ---------------------------------------------------------------------------
__global__ __launch_bounds__(256, 4) void fused_kernel(
    const float* __restrict__ input,
    const float* __restrict__ b1,
    const float* __restrict__ b2,
    const unsigned* __restrict__ wfrag1,
    const unsigned* __restrict__ wfrag2,
    const float* __restrict__ fc7,
    const float* __restrict__ fc_b,
    const float* __restrict__ taubp,
    float* __restrict__ params)
{
    __shared__ unsigned lds_in[1960];                       // [5][392]
    __shared__ __align__(16) unsigned short h1f[7200];      // [100][72]
    __shared__ float red[32];

    const int t = threadIdx.x, b = blockIdx.x;
    const int lane = t & 63, w = t >> 6;
    const int lq = lane & 31, hi = lane >> 5;

    // ---- zero lds_in + h1 halo rows (0,1,98,99) ----
    for (int i = t; i < 1960; i += 256) lds_in[i] = 0u;
    if (t < 144) {
        const int r = t / 36, wd = t - r * 36;
        const int row = (r < 2) ? r : 96 + r;
        ((unsigned*)h1f)[row * 36 + wd] = 0u;
    }
    __syncthreads();
    const float* inb = input + (size_t)b * 1920;
    for (int i = t; i < 1920; i += 256) {
        const int ic = i / 384, x = i - ic * 384;
        lds_in[ic * 392 + 3 + x] = packsplit(inb[i]);
    }
    __syncthreads();

    // ------------- conv1: C[pos=384][oc=64], K'=48 (3 ks of 16) -------------
    // wave w owns mtiles w*3..w*3+2 (32 pos each), both oc-ntiles.
    const i32x4* w1f = (const i32x4*)wfrag1;
    Frag c1b[3][2][2];                       // [ks][nt][part]
    #pragma unroll
    for (int ks = 0; ks < 3; ++ks)
        #pragma unroll
        for (int nt = 0; nt < 2; ++nt) {
            const int fi = ((ks * 2 + nt) * 64 + lane) * 2;
            c1b[ks][nt][0].q = w1f[fi];
            c1b[ks][nt][1].q = w1f[fi + 1];
        }
    float b1v[2];
    #pragma unroll
    for (int nt = 0; nt < 2; ++nt) b1v[nt] = b1[nt * 32 + lq];

    #pragma unroll
    for (int m = 0; m < 3; ++m) {
        const int mtile = w * 3 + m;
        f32x16 acc0 = ZERO16, acc1 = ZERO16;
        #pragma unroll
        for (int ks = 0; ks < 3; ++ks) {
            // ic = ks*2+hi; ks==2,hi==1 -> ic=5 (virtual zero row): clamp+mask
            const int rowoff = (ks == 2) ? 4 * 392 : (ks * 2 + hi) * 392;
            const unsigned* src = lds_in + rowoff + mtile * 32 + lq;
            unsigned p[8];
            #pragma unroll
            for (int j = 0; j < 8; ++j) p[j] = src[j];
            Frag ah, al;
            #pragma unroll
            for (int wj = 0; wj < 4; ++wj) {
                ah.u[wj] = __builtin_amdgcn_perm(p[2*wj+1], p[2*wj], 0x07060302u);
                al.u[wj] = __builtin_amdgcn_perm(p[2*wj+1], p[2*wj], 0x05040100u);
            }
            if (ks == 2) {
                #pragma unroll
                for (int wj = 0; wj < 4; ++wj) {
                    ah.u[wj] = hi ? 0 : ah.u[wj];
                    al.u[wj] = hi ? 0 : al.u[wj];
                }
            }
            acc0 = __builtin_amdgcn_mfma_f32_32x32x16_bf16(ah.v, c1b[ks][0][0].v, acc0, 0, 0, 0);
            acc1 = __builtin_amdgcn_mfma_f32_32x32x16_bf16(ah.v, c1b[ks][1][0].v, acc1, 0, 0, 0);
            acc0 = __builtin_amdgcn_mfma_f32_32x32x16_bf16(ah.v, c1b[ks][0][1].v, acc0, 0, 0, 0);
            acc1 = __builtin_amdgcn_mfma_f32_32x32x16_bf16(ah.v, c1b[ks][1][1].v, acc1, 0, 0, 0);
            acc0 = __builtin_amdgcn_mfma_f32_32x32x16_bf16(al.v, c1b[ks][0][0].v, acc0, 0, 0, 0);
            acc1 = __builtin_amdgcn_mfma_f32_32x32x16_bf16(al.v, c1b[ks][1][0].v, acc1, 0, 0, 0);
        }
        // pool4 + relu + single-fp16 write: reg-quad q = rows 8q+4hi+0..3
        #pragma unroll
        for (int q = 0; q < 4; ++q) {
            const int c = mtile * 8 + 2 * q + hi;
            {
                float s = 0.f;
                #pragma unroll
                for (int r4 = 0; r4 < 4; ++r4) s += fmaxf(acc0[q*4+r4] + b1v[0], 0.f);
                h1f[(c + 2) * 72 + lq] = f16_rne(0.25f * s);
            }
            {
                float s = 0.f;
                #pragma unroll
                for (int r4 = 0; r4 < 4; ++r4) s += fmaxf(acc1[q*4+r4] + b1v[1], 0.f);
                h1f[(c + 2) * 72 + 32 + lq] = f16_rne(0.25f * s);
            }
        }
    }
    __syncthreads();

    // ------ conv2: 20 k-steps (dk*4+icc), wave = ntile w, mtiles 0..2 ------
    // A = h1 fp16 single; B = 1024*w2 split fp16 (bh,bl); 2 MFMA per (s,mt).
    f32x16 acc2[3] = {ZERO16, ZERO16, ZERO16};

    const i32x4* aF = (const i32x4*)(h1f + lq * 72 + hi * 8);
    const i32x4* w2f = (const i32x4*)wfrag2;
    Frag b2h[2], b2l[2];                     // B double-buffer
    Frag a2[2];                              // A rolling buffer

    {   // prologue: B(step0), A(step0, mt0)
        const int fi = (w * 64 + lane) * 2;
        b2h[0].q = w2f[fi];
        b2l[0].q = w2f[fi + 1];
        a2[0].q = aF[0];
    }

    #pragma unroll
    for (int s = 0; s < 20; ++s) {
        const int sb = s & 1, snb = sb ^ 1;
        if (s < 19) {
            const int fi = (((s + 1) * 4 + w) * 64 + lane) * 2;
            b2h[snb].q = w2f[fi];
            b2l[snb].q = w2f[fi + 1];
        }
        #pragma unroll
        for (int mt = 0; mt < 3; ++mt) {
            const int it = s * 3 + mt, cur = it & 1, nxt = cur ^ 1;
            if (it < 59) {
                const int nit = it + 1, nmt = nit % 3, ns = nit / 3;
                const int off = (nmt * 32 + (ns >> 2)) * 9 + (ns & 3) * 2;
                a2[nxt].q = aF[off];
            }
            acc2[mt] = __builtin_amdgcn_mfma_f32_32x32x16_f16(a2[cur].h, b2h[sb].h, acc2[mt], 0, 0, 0);
            acc2[mt] = __builtin_amdgcn_mfma_f32_32x32x16_f16(a2[cur].h, b2l[sb].h, acc2[mt], 0, 0, 0);
        }
    }

    // ---- epilogue: unscale (2^-10) + bias + relu + pool4 -> feat; fc7 ----
    float dot[7] = {0.f, 0.f, 0.f, 0.f, 0.f, 0.f, 0.f};
    {
        const float b2v = b2[w * 32 + lq];
        #pragma unroll
        for (int mt = 0; mt < 3; ++mt) {
            #pragma unroll
            for (int q = 0; q < 4; ++q) {
                float s = 0.f;
                #pragma unroll
                for (int r4 = 0; r4 < 4; ++r4)
                    s += fmaxf(acc2[mt][q*4+r4] * 0.0009765625f + b2v, 0.f);
                s *= 0.25f;
                const int fq = mt * 8 + 2 * q + hi;
                const int idx = (w * 32 + lq) * 24 + fq;
                const f32x4* fp = (const f32x4*)(fc7 + idx * 8);
                const f32x4 f0 = fp[0], f1 = fp[1];
                dot[0] += s * f0[0]; dot[1] += s * f0[1];
                dot[2] += s * f0[2]; dot[3] += s * f0[3];
                dot[4] += s * f1[0]; dot[5] += s * f1[1];
                dot[6] += s * f1[2];
            }
        }
    }

    #pragma unroll
    for (int j = 0; j < 7; ++j) {
        float s = dot[j];
        #pragma unroll
        for (int off = 32; off; off >>= 1) s += __shfl_down(s, off);
        if (lane == 0) red[w * 8 + j] = s;
    }
    __syncthreads();
    if (t < 7) {
        float s = red[t] + red[8 + t] + red[16 + t] + red[24 + t];
        s += (t < 6) ? fc_b[t] : taubp[0];
        params[(size_t)b * 8 + t] = s;
    }
}

// ---------------------------------------------------------------------------
// Kernel 2: DMP rollout — 1 thread per batch element.
// ---------------------------------------------------------------------------
__global__ void rollout_kernel(const float* __restrict__ params,
                               const float* __restrict__ y0,
                               float* __restrict__ out) {
    const int b = blockIdx.x * 256 + threadIdx.x;
    const float* p = params + (size_t)b * 8;
    const float goal = p[0];
    const float w0 = p[1], w1 = p[2], w2 = p[3], w3 = p[4], w4 = p[5];
    const float tau = p[6];
    const float y0v = y0[b];

    const float c0 = 1.0f;
    const float c1 = 0.77880078307140486825f;
    const float c2 = 0.60653065971263342360f;
    const float c3 = 0.47236655274101470714f;
    const float c4 = 0.36787944117144232160f;
    const float inv2s = -0.5f / 11.180339887498949f;
    const float e0 = inv2s * c0, e1 = inv2s * c1, e2 = inv2s * c2,
                e3 = inv2s * c3, e4 = inv2s * c4;

    float x = 1.0f, y = y0v, z = 0.01f * tau;
    const float td = tau * 0.01f;
    const float gmy0 = goal - y0v;
    float* ob = out + (size_t)b * 101;
    ob[0] = y0v;
    for (int s = 1; s <= 100; ++s) {
        x = x - x * td;
        const float d0 = x - c0, d1 = x - c1, d2 = x - c2, d3 = x - c3, d4 = x - c4;
        const float p0 = __expf(e0 * d0 * d0);
        const float p1 = __expf(e1 * d1 * d1);
        const float p2 = __expf(e2 * d2 * d2);
        const float p3 = __expf(e3 * d3 * d3);
        const float p4 = __expf(e4 * d4 * d4);
        const float den = p0 + p1 + p2 + p3 + p4;
        const float num = w0 * p0 + w1 * p1 + w2 * p2 + w3 * p3 + w4 * p4;
        const float fx = (num / den) * x * gmy0;
        const float dz = 25.0f * (6.25f * (goal - y) - z) + fx;
        const float dy = z;
        y += dy * td;
        z += dz * td;
        ob[s] = y;
    }
}

extern "C" void kernel_launch(void* const* d_in, const int* in_sizes, int n_in,
                              void* d_out, int out_size, void* d_ws, size_t ws_size,
                              hipStream_t stream) {
    const float* input = (const float*)d_in[0];
    const float* y0    = (const float*)d_in[1];
    const float* w1    = (const float*)d_in[2];
    const float* b1    = (const float*)d_in[3];
    const float* w2    = (const float*)d_in[4];
    const float* b2    = (const float*)d_in[5];
    const float* fc_w  = (const float*)d_in[6];
    const float* fc_b  = (const float*)d_in[7];
    const float* L_w   = (const float*)d_in[8];
    const float* L_b   = (const float*)d_in[9];
    float* out = (float*)d_out;

    float* ws      = (float*)d_ws;
    float* fc7     = ws;                          // 24576 f
    float* taub    = ws + 24576;                  // pad to 64
    float* params  = ws + 24640;                  // 32768 f
    unsigned* wfrag1 = (unsigned*)(ws + 57408);   // 3072 u32 (pad to 4096)
    unsigned* wfrag2 = wfrag1 + 4096;             // 40960 u32

    const int B = in_sizes[1];                    // 4096

    precompute_kernel<<<69, 256, 0, stream>>>(w1, w2, fc_w, fc_b, L_w, L_b,
                                              fc7, taub, wfrag1, wfrag2);
    fused_kernel<<<B, 256, 0, stream>>>(input, b1, b2, wfrag1, wfrag2,
                                        fc7, fc_b, taub, params);
    rollout_kernel<<<B / 256, 256, 0, stream>>>(params, y0, out);
}

// Round 11
// 136.309 us; speedup vs baseline: 3.3879x; 1.0304x over previous
//
#include <hip/hip_runtime.h>
#include <math.h>

// ---------------------------------------------------------------------------
// B=4096. conv1 (64,5,7) pad3 + relu + pool4 -> h1 (64,96)
//         conv2 (128,64,5) pad2 + relu + pool4 -> feat (128,24)
//         fc: only cols 0..5 of (404,3072) + tau = feat·(L_w@fc_w) + const.
// Precision: conv1 = 3-term split-bf16 (err ~2^-16/prod). conv2 = 2-term
// fp16: A = h1 single fp16, B = 1024*w2 split fp16 hi/lo (epilogue *2^-10).
// Measured absmax 64 vs threshold 460.8.
// Both convs on v_mfma_f32_32x32x16_{bf16,f16}.
// C/D (m74/m101): col=lane&31(oc), row=(reg&3)+8*(reg>>2)+4*(lane>>5) ->
// reg-quads = 4 consecutive pos -> pool4 in-register.
// R11: conv2 per-step A-block double-buffer (3 frags prefetched a full step
// ahead, acc rotation distance 3); conv1 distance-1 p-buffer. Regs ~124
// under the (256,4) cap of 128 — NO launch_bounds above 4 (R9 spill lesson).
// ---------------------------------------------------------------------------

typedef short bf16x8 __attribute__((ext_vector_type(8)));
typedef _Float16 f16x8 __attribute__((ext_vector_type(8)));
typedef float f32x4  __attribute__((ext_vector_type(4)));
typedef float f32x16 __attribute__((ext_vector_type(16)));
typedef int   i32x4  __attribute__((ext_vector_type(4)));

union Frag { int u[4]; i32x4 q; bf16x8 v; f16x8 h; };
union H16 { _Float16 hf; unsigned short us; };

__device__ __forceinline__ unsigned bf16_rne(float f) {
    unsigned u = __float_as_uint(f);
    return (u + 0x7fffu + ((u >> 16) & 1u)) >> 16;
}
__device__ __forceinline__ unsigned packsplit(float f) {
    unsigned hi = bf16_rne(f);
    float lo = f - __uint_as_float(hi << 16);
    return (hi << 16) | bf16_rne(lo);
}
__device__ __forceinline__ unsigned short f16_rne(float f) {
    H16 c; c.hf = (_Float16)f; return c.us;
}

#define ZERO16 {0.f,0.f,0.f,0.f,0.f,0.f,0.f,0.f,0.f,0.f,0.f,0.f,0.f,0.f,0.f,0.f}

// ---------------------------------------------------------------------------
// Kernel 0 (merged): fc7 (blocks 0..47), taub+wfrag1 (48), wfrag2 (49..68).
//  wfrag1: [ks3][nt2][lane64][part2][4u32] bf16 split; k'=ks*16+(lane>>5)*8+j,
//          ic=k'>>3, dk=k'&7 (ic==5 -> zero)
//  wfrag2: [step20][nt4][lane64][part2][4u32] fp16 of 1024*w2; part0=hi,
//          part1=lo; step=dk*4+icc; k_ic=icc*16+(lane>>5)*8+j
// ---------------------------------------------------------------------------
__global__ void precompute_kernel(const float* __restrict__ w1,
                                  const float* __restrict__ w2,
                                  const float* __restrict__ fc_w,
                                  const float* __restrict__ fc_b,
                                  const float* __restrict__ L_w,
                                  const float* __restrict__ L_b,
                                  float* __restrict__ fc7,
                                  float* __restrict__ taub,
                                  unsigned* __restrict__ wfrag1,
                                  unsigned* __restrict__ wfrag2) {
    const int t = threadIdx.x, bb = blockIdx.x;
    if (bb < 48) {
        __shared__ float part[3][64];
        const int k = bb * 64 + (t & 63), jc = t >> 6;
        const int j0 = jc * 101;
        float s = 0.f;
        #pragma unroll 8
        for (int j = j0; j < j0 + 101; ++j) s += L_w[j] * fc_w[j * 3072 + k];
        if (jc) part[jc - 1][t & 63] = s;
        __syncthreads();
        if (jc == 0) {
            const int kk = t & 63;
            float r[8];
            #pragma unroll
            for (int j = 0; j < 6; ++j) r[j] = fc_w[j * 3072 + k];
            r[6] = s + part[0][kk] + part[1][kk] + part[2][kk];
            r[7] = 0.f;
            #pragma unroll
            for (int j = 0; j < 8; ++j) fc7[k * 8 + j] = r[j];
        }
    } else if (bb == 48) {
        if (t < 64) {
            float s = 0.f;
            for (int j = t; j < 404; j += 64) s += L_w[j] * fc_b[j];
            #pragma unroll
            for (int off = 32; off; off >>= 1) s += __shfl_down(s, off);
            if (t == 0) taub[0] = s + L_b[0];
        }
        for (int i = t; i < 768; i += 256) {        // conv1 frags (bf16 split)
            const int part = i & 1, lane = (i >> 1) & 63,
                      nt = (i >> 7) & 1, ks = i >> 8;        // 0..2
            const int oc = nt * 32 + (lane & 31);
            unsigned h[8];
            #pragma unroll
            for (int j = 0; j < 8; ++j) {
                const int kp = ks * 16 + (lane >> 5) * 8 + j;  // k' = ic*8+dk
                const int ic = kp >> 3, dk = kp & 7;
                float v = (ic < 5 && dk < 7) ? w1[oc * 35 + ic * 7 + dk] : 0.f;
                unsigned hb = bf16_rne(v);
                if (part) hb = bf16_rne(v - __uint_as_float(hb << 16));
                h[j] = hb;
            }
            #pragma unroll
            for (int wj = 0; wj < 4; ++wj)
                wfrag1[i * 4 + wj] = (h[2 * wj + 1] << 16) | h[2 * wj];
        }
    } else {                                        // conv2 frags (fp16 x1024)
        const int base = (bb - 49) * 512;
        #pragma unroll
        for (int r = 0; r < 2; ++r) {
            const int i = base + r * 256 + t;
            const int part = i & 1, lane = (i >> 1) & 63,
                      nt = (i >> 7) & 3, step = i >> 9;       // 0..19
            const int oc = nt * 32 + (lane & 31);
            const int dk = step >> 2, icc = step & 3;
            unsigned short h[8];
            #pragma unroll
            for (int j = 0; j < 8; ++j) {
                const int ic = icc * 16 + (lane >> 5) * 8 + j;  // k = ic
                const float v = w2[oc * 320 + ic * 5 + dk] * 1024.0f;
                H16 c; c.hf = (_Float16)v;
                if (part) { const float rr = v - (float)c.hf; c.hf = (_Float16)rr; }
                h[j] = c.us;
            }
            #pragma unroll
            for (int wj = 0; wj < 4; ++wj)
                wfrag2[i * 4 + wj] = ((unsigned)h[2 * wj + 1] << 16) | h[2 * wj];
        }
    }
}

// ---------------------------------------------------------------------------
// Kernel 1: fused conv1+conv2+fc, one batch per block, 4 blocks/CU.
// LDS (22368 B): lds_in u32[5][392] packed bf16 hi|lo (halo cols zero),
//   h1f fp16[100][72] (rows 0,1,98,99 halo-zero), red f32[32].
// ---------------------------------------------------------------------------
__global__ __launch_bounds__(256, 4) void fused_kernel(
    const float* __restrict__ input,
    const float* __restrict__ b1,
    const float* __restrict__ b2,
    const unsigned* __restrict__ wfrag1,
    const unsigned* __restrict__ wfrag2,
    const float* __restrict__ fc7,
    const float* __restrict__ fc_b,
    const float* __restrict__ taubp,
    float* __restrict__ params)
{
    __shared__ unsigned lds_in[1960];                       // [5][392]
    __shared__ __align__(16) unsigned short h1f[7200];      // [100][72]
    __shared__ float red[32];

    const int t = threadIdx.x, b = blockIdx.x;
    const int lane = t & 63, w = t >> 6;
    const int lq = lane & 31, hi = lane >> 5;

    // ---- zero lds_in + h1 halo rows (0,1,98,99) ----
    for (int i = t; i < 1960; i += 256) lds_in[i] = 0u;
    if (t < 144) {
        const int r = t / 36, wd = t - r * 36;
        const int row = (r < 2) ? r : 96 + r;
        ((unsigned*)h1f)[row * 36 + wd] = 0u;
    }
    __syncthreads();
    const float* inb = input + (size_t)b * 1920;
    for (int i = t; i < 1920; i += 256) {
        const int ic = i / 384, x = i - ic * 384;
        lds_in[ic * 392 + 3 + x] = packsplit(inb[i]);
    }
    __syncthreads();

    // ------------- conv1: C[pos=384][oc=64], K'=48 (3 ks of 16) -------------
    // wave w owns mtiles w*3..w*3+2 (32 pos each), both oc-ntiles.
    // Distance-1 p-buffer across the 9 (m,ks) iterations.
    const i32x4* w1f = (const i32x4*)wfrag1;
    Frag c1b[3][2][2];                       // [ks][nt][part]
    #pragma unroll
    for (int ks = 0; ks < 3; ++ks)
        #pragma unroll
        for (int nt = 0; nt < 2; ++nt) {
            const int fi = ((ks * 2 + nt) * 64 + lane) * 2;
            c1b[ks][nt][0].q = w1f[fi];
            c1b[ks][nt][1].q = w1f[fi + 1];
        }
    float b1v[2];
    #pragma unroll
    for (int nt = 0; nt < 2; ++nt) b1v[nt] = b1[nt * 32 + lq];

    unsigned pbuf[2][8];
    {   // prologue: (m=0, ks=0): ic = hi
        const unsigned* src = lds_in + hi * 392 + (w * 3) * 32 + lq;
        #pragma unroll
        for (int j = 0; j < 8; ++j) pbuf[0][j] = src[j];
    }
    #pragma unroll
    for (int m = 0; m < 3; ++m) {
        const int mtile = w * 3 + m;
        f32x16 acc0 = ZERO16, acc1 = ZERO16;
        #pragma unroll
        for (int ks = 0; ks < 3; ++ks) {
            const int it = m * 3 + ks, cur = it & 1, nxt = cur ^ 1;
            if (it < 8) {
                const int nit = it + 1, nm = nit / 3, nks = nit % 3;
                const int rowoff = (nks == 2) ? 4 * 392 : (nks * 2 + hi) * 392;
                const unsigned* src = lds_in + rowoff + (w * 3 + nm) * 32 + lq;
                #pragma unroll
                for (int j = 0; j < 8; ++j) pbuf[nxt][j] = src[j];
            }
            Frag ah, al;
            #pragma unroll
            for (int wj = 0; wj < 4; ++wj) {
                ah.u[wj] = __builtin_amdgcn_perm(pbuf[cur][2*wj+1], pbuf[cur][2*wj], 0x07060302u);
                al.u[wj] = __builtin_amdgcn_perm(pbuf[cur][2*wj+1], pbuf[cur][2*wj], 0x05040100u);
            }
            if (ks == 2) {     // ic = ks*2+hi = 5 for hi=1: virtual zero row
                #pragma unroll
                for (int wj = 0; wj < 4; ++wj) {
                    ah.u[wj] = hi ? 0 : ah.u[wj];
                    al.u[wj] = hi ? 0 : al.u[wj];
                }
            }
            acc0 = __builtin_amdgcn_mfma_f32_32x32x16_bf16(ah.v, c1b[ks][0][0].v, acc0, 0, 0, 0);
            acc1 = __builtin_amdgcn_mfma_f32_32x32x16_bf16(ah.v, c1b[ks][1][0].v, acc1, 0, 0, 0);
            acc0 = __builtin_amdgcn_mfma_f32_32x32x16_bf16(ah.v, c1b[ks][0][1].v, acc0, 0, 0, 0);
            acc1 = __builtin_amdgcn_mfma_f32_32x32x16_bf16(ah.v, c1b[ks][1][1].v, acc1, 0, 0, 0);
            acc0 = __builtin_amdgcn_mfma_f32_32x32x16_bf16(al.v, c1b[ks][0][0].v, acc0, 0, 0, 0);
            acc1 = __builtin_amdgcn_mfma_f32_32x32x16_bf16(al.v, c1b[ks][1][0].v, acc1, 0, 0, 0);
        }
        // pool4 + relu + single-fp16 write: reg-quad q = rows 8q+4hi+0..3
        #pragma unroll
        for (int q = 0; q < 4; ++q) {
            const int c = mtile * 8 + 2 * q + hi;
            {
                float s = 0.f;
                #pragma unroll
                for (int r4 = 0; r4 < 4; ++r4) s += fmaxf(acc0[q*4+r4] + b1v[0], 0.f);
                h1f[(c + 2) * 72 + lq] = f16_rne(0.25f * s);
            }
            {
                float s = 0.f;
                #pragma unroll
                for (int r4 = 0; r4 < 4; ++r4) s += fmaxf(acc1[q*4+r4] + b1v[1], 0.f);
                h1f[(c + 2) * 72 + 32 + lq] = f16_rne(0.25f * s);
            }
        }
    }
    __syncthreads();

    // ------ conv2: 20 k-steps (dk*4+icc), wave = ntile w, mtiles 0..2 ------
    // A = h1 fp16 single; B = 1024*w2 split fp16.
    // Per-step A-block double-buffer: all 3 mt frags for step s+1 load during
    // step s's 6 MFMAs; accumulators rotate mt0->mt1->mt2 (dep distance 3).
    f32x16 acc2[3] = {ZERO16, ZERO16, ZERO16};

    const i32x4* aF = (const i32x4*)(h1f + lq * 72 + hi * 8);
    const i32x4* w2f = (const i32x4*)wfrag2;
    Frag b2h[2], b2l[2];                     // B double-buffer
    Frag a2f[2][3];                          // per-step A block, dbuf

    {   // prologue: B(step0), A(step0, mt 0..2)
        const int fi = (w * 64 + lane) * 2;
        b2h[0].q = w2f[fi];
        b2l[0].q = w2f[fi + 1];
        #pragma unroll
        for (int mt = 0; mt < 3; ++mt) a2f[0][mt].q = aF[mt * 288];
    }

    #pragma unroll
    for (int s = 0; s < 20; ++s) {
        const int sb = s & 1, nb = sb ^ 1;
        if (s < 19) {
            const int fi = (((s + 1) * 4 + w) * 64 + lane) * 2;
            b2h[nb].q = w2f[fi];
            b2l[nb].q = w2f[fi + 1];
            const int dkn = (s + 1) >> 2, iccn = (s + 1) & 3;
            #pragma unroll
            for (int mt = 0; mt < 3; ++mt)
                a2f[nb][mt].q = aF[(mt * 32 + dkn) * 9 + iccn * 2];
        }
        #pragma unroll
        for (int mt = 0; mt < 3; ++mt)
            acc2[mt] = __builtin_amdgcn_mfma_f32_32x32x16_f16(a2f[sb][mt].h, b2h[sb].h, acc2[mt], 0, 0, 0);
        #pragma unroll
        for (int mt = 0; mt < 3; ++mt)
            acc2[mt] = __builtin_amdgcn_mfma_f32_32x32x16_f16(a2f[sb][mt].h, b2l[sb].h, acc2[mt], 0, 0, 0);
    }

    // ---- epilogue: unscale (2^-10) + bias + relu + pool4 -> feat; fc7 ----
    float dot[7] = {0.f, 0.f, 0.f, 0.f, 0.f, 0.f, 0.f};
    {
        const float b2v = b2[w * 32 + lq];
        #pragma unroll
        for (int mt = 0; mt < 3; ++mt) {
            #pragma unroll
            for (int q = 0; q < 4; ++q) {
                float s = 0.f;
                #pragma unroll
                for (int r4 = 0; r4 < 4; ++r4)
                    s += fmaxf(acc2[mt][q*4+r4] * 0.0009765625f + b2v, 0.f);
                s *= 0.25f;
                const int fq = mt * 8 + 2 * q + hi;
                const int idx = (w * 32 + lq) * 24 + fq;
                const f32x4* fp = (const f32x4*)(fc7 + idx * 8);
                const f32x4 f0 = fp[0], f1 = fp[1];
                dot[0] += s * f0[0]; dot[1] += s * f0[1];
                dot[2] += s * f0[2]; dot[3] += s * f0[3];
                dot[4] += s * f1[0]; dot[5] += s * f1[1];
                dot[6] += s * f1[2];
            }
        }
    }

    #pragma unroll
    for (int j = 0; j < 7; ++j) {
        float s = dot[j];
        #pragma unroll
        for (int off = 32; off; off >>= 1) s += __shfl_down(s, off);
        if (lane == 0) red[w * 8 + j] = s;
    }
    __syncthreads();
    if (t < 7) {
        float s = red[t] + red[8 + t] + red[16 + t] + red[24 + t];
        s += (t < 6) ? fc_b[t] : taubp[0];
        params[(size_t)b * 8 + t] = s;
    }
}

// ---------------------------------------------------------------------------
// Kernel 2: DMP rollout — 1 thread per batch element.
// ---------------------------------------------------------------------------
__global__ void rollout_kernel(const float* __restrict__ params,
                               const float* __restrict__ y0,
                               float* __restrict__ out) {
    const int b = blockIdx.x * 256 + threadIdx.x;
    const float* p = params + (size_t)b * 8;
    const float goal = p[0];
    const float w0 = p[1], w1 = p[2], w2 = p[3], w3 = p[4], w4 = p[5];
    const float tau = p[6];
    const float y0v = y0[b];

    const float c0 = 1.0f;
    const float c1 = 0.77880078307140486825f;
    const float c2 = 0.60653065971263342360f;
    const float c3 = 0.47236655274101470714f;
    const float c4 = 0.36787944117144232160f;
    const float inv2s = -0.5f / 11.180339887498949f;
    const float e0 = inv2s * c0, e1 = inv2s * c1, e2 = inv2s * c2,
                e3 = inv2s * c3, e4 = inv2s * c4;

    float x = 1.0f, y = y0v, z = 0.01f * tau;
    const float td = tau * 0.01f;
    const float gmy0 = goal - y0v;
    float* ob = out + (size_t)b * 101;
    ob[0] = y0v;
    for (int s = 1; s <= 100; ++s) {
        x = x - x * td;
        const float d0 = x - c0, d1 = x - c1, d2 = x - c2, d3 = x - c3, d4 = x - c4;
        const float p0 = __expf(e0 * d0 * d0);
        const float p1 = __expf(e1 * d1 * d1);
        const float p2 = __expf(e2 * d2 * d2);
        const float p3 = __expf(e3 * d3 * d3);
        const float p4 = __expf(e4 * d4 * d4);
        const float den = p0 + p1 + p2 + p3 + p4;
        const float num = w0 * p0 + w1 * p1 + w2 * p2 + w3 * p3 + w4 * p4;
        const float fx = (num / den) * x * gmy0;
        const float dz = 25.0f * (6.25f * (goal - y) - z) + fx;
        const float dy = z;
        y += dy * td;
        z += dz * td;
        ob[s] = y;
    }
}

extern "C" void kernel_launch(void* const* d_in, const int* in_sizes, int n_in,
                              void* d_out, int out_size, void* d_ws, size_t ws_size,
                              hipStream_t stream) {
    const float* input = (const float*)d_in[0];
    const float* y0    = (const float*)d_in[1];
    const float* w1    = (const float*)d_in[2];
    const float* b1    = (const float*)d_in[3];
    const float* w2    = (const float*)d_in[4];
    const float* b2    = (const float*)d_in[5];
    const float* fc_w  = (const float*)d_in[6];
    const float* fc_b  = (const float*)d_in[7];
    const float* L_w   = (const float*)d_in[8];
    const float* L_b   = (const float*)d_in[9];
    float* out = (float*)d_out;

    float* ws      = (float*)d_ws;
    float* fc7     = ws;                          // 24576 f
    float* taub    = ws + 24576;                  // pad to 64
    float* params  = ws + 24640;                  // 32768 f
    unsigned* wfrag1 = (unsigned*)(ws + 57408);   // 3072 u32 (pad to 4096)
    unsigned* wfrag2 = wfrag1 + 4096;             // 40960 u32

    const int B = in_sizes[1];                    // 4096

    precompute_kernel<<<69, 256, 0, stream>>>(w1, w2, fc_w, fc_b, L_w, L_b,
                                              fc7, taub, wfrag1, wfrag2);
    fused_kernel<<<B, 256, 0, stream>>>(input, b1, b2, wfrag1, wfrag2,
                                        fc7, fc_b, taub, params);
    rollout_kernel<<<B / 256, 256, 0, stream>>>(params, y0, out);
}

// Round 12
// 132.800 us; speedup vs baseline: 3.4775x; 1.0264x over previous
//
#include <hip/hip_runtime.h>
#include <math.h>

// ---------------------------------------------------------------------------
// B=4096. conv1 (64,5,7) pad3 + relu + pool4 -> h1 (64,96)
//         conv2 (128,64,5) pad2 + relu + pool4 -> feat (128,24)
//         fc: only cols 0..5 of (404,3072) + tau = feat·(L_w@fc_w) + const.
// Precision: conv1 = 3-term split-bf16 (err ~2^-16/prod). conv2 = 2-term
// fp16: A = h1 single fp16, B = 1024*w2 split fp16 hi/lo (epilogue *2^-10).
// Measured absmax 64 vs threshold 460.8.
// Both convs on v_mfma_f32_32x32x16_{bf16,f16}.
// C/D (m74/m101): col=lane&31(oc), row=(reg&3)+8*(reg>>2)+4*(lane>>5) ->
// reg-quads = 4 consecutive pos -> pool4 in-register.
// R12: fc7 TRANSPOSED to [fq24][j8][oc128] -> epilogue loads coalesced
// (was 32B/lane at stride 768B = ~32 cache lines per load); s_setprio(1)
// around MFMA clusters (independent blocks at different phases on a CU).
// ---------------------------------------------------------------------------

typedef short bf16x8 __attribute__((ext_vector_type(8)));
typedef _Float16 f16x8 __attribute__((ext_vector_type(8)));
typedef float f32x4  __attribute__((ext_vector_type(4)));
typedef float f32x16 __attribute__((ext_vector_type(16)));
typedef int   i32x4  __attribute__((ext_vector_type(4)));

union Frag { int u[4]; i32x4 q; bf16x8 v; f16x8 h; };
union H16 { _Float16 hf; unsigned short us; };

__device__ __forceinline__ unsigned bf16_rne(float f) {
    unsigned u = __float_as_uint(f);
    return (u + 0x7fffu + ((u >> 16) & 1u)) >> 16;
}
__device__ __forceinline__ unsigned packsplit(float f) {
    unsigned hi = bf16_rne(f);
    float lo = f - __uint_as_float(hi << 16);
    return (hi << 16) | bf16_rne(lo);
}
__device__ __forceinline__ unsigned short f16_rne(float f) {
    H16 c; c.hf = (_Float16)f; return c.us;
}

#define ZERO16 {0.f,0.f,0.f,0.f,0.f,0.f,0.f,0.f,0.f,0.f,0.f,0.f,0.f,0.f,0.f,0.f}

// ---------------------------------------------------------------------------
// Kernel 0 (merged): fc7T (blocks 0..47), taub+wfrag1 (48), wfrag2 (49..68).
//  fc7T: [fq24][j8][oc128] f32; j0..5 = fc_w cols, j6 = L_w@fc_w, j7 = 0
//  wfrag1: [ks3][nt2][lane64][part2][4u32] bf16 split; k'=ks*16+(lane>>5)*8+j,
//          ic=k'>>3, dk=k'&7 (ic==5 -> zero)
//  wfrag2: [step20][nt4][lane64][part2][4u32] fp16 of 1024*w2; part0=hi,
//          part1=lo; step=dk*4+icc; k_ic=icc*16+(lane>>5)*8+j
// ---------------------------------------------------------------------------
__global__ void precompute_kernel(const float* __restrict__ w1,
                                  const float* __restrict__ w2,
                                  const float* __restrict__ fc_w,
                                  const float* __restrict__ fc_b,
                                  const float* __restrict__ L_w,
                                  const float* __restrict__ L_b,
                                  float* __restrict__ fc7,
                                  float* __restrict__ taub,
                                  unsigned* __restrict__ wfrag1,
                                  unsigned* __restrict__ wfrag2) {
    const int t = threadIdx.x, bb = blockIdx.x;
    if (bb < 48) {
        __shared__ float part[3][64];
        const int k = bb * 64 + (t & 63), jc = t >> 6;
        const int j0 = jc * 101;
        float s = 0.f;
        #pragma unroll 8
        for (int j = j0; j < j0 + 101; ++j) s += L_w[j] * fc_w[j * 3072 + k];
        if (jc) part[jc - 1][t & 63] = s;
        __syncthreads();
        if (jc == 0) {
            const int kk = t & 63;
            const int oc = k / 24, fq = k - oc * 24;
            float r[8];
            #pragma unroll
            for (int j = 0; j < 6; ++j) r[j] = fc_w[j * 3072 + k];
            r[6] = s + part[0][kk] + part[1][kk] + part[2][kk];
            r[7] = 0.f;
            #pragma unroll
            for (int j = 0; j < 8; ++j) fc7[fq * 1024 + j * 128 + oc] = r[j];
        }
    } else if (bb == 48) {
        if (t < 64) {
            float s = 0.f;
            for (int j = t; j < 404; j += 64) s += L_w[j] * fc_b[j];
            #pragma unroll
            for (int off = 32; off; off >>= 1) s += __shfl_down(s, off);
            if (t == 0) taub[0] = s + L_b[0];
        }
        for (int i = t; i < 768; i += 256) {        // conv1 frags (bf16 split)
            const int part = i & 1, lane = (i >> 1) & 63,
                      nt = (i >> 7) & 1, ks = i >> 8;        // 0..2
            const int oc = nt * 32 + (lane & 31);
            unsigned h[8];
            #pragma unroll
            for (int j = 0; j < 8; ++j) {
                const int kp = ks * 16 + (lane >> 5) * 8 + j;  // k' = ic*8+dk
                const int ic = kp >> 3, dk = kp & 7;
                float v = (ic < 5 && dk < 7) ? w1[oc * 35 + ic * 7 + dk] : 0.f;
                unsigned hb = bf16_rne(v);
                if (part) hb = bf16_rne(v - __uint_as_float(hb << 16));
                h[j] = hb;
            }
            #pragma unroll
            for (int wj = 0; wj < 4; ++wj)
                wfrag1[i * 4 + wj] = (h[2 * wj + 1] << 16) | h[2 * wj];
        }
    } else {                                        // conv2 frags (fp16 x1024)
        const int base = (bb - 49) * 512;
        #pragma unroll
        for (int r = 0; r < 2; ++r) {
            const int i = base + r * 256 + t;
            const int part = i & 1, lane = (i >> 1) & 63,
                      nt = (i >> 7) & 3, step = i >> 9;       // 0..19
            const int oc = nt * 32 + (lane & 31);
            const int dk = step >> 2, icc = step & 3;
            unsigned short h[8];
            #pragma unroll
            for (int j = 0; j < 8; ++j) {
                const int ic = icc * 16 + (lane >> 5) * 8 + j;  // k = ic
                const float v = w2[oc * 320 + ic * 5 + dk] * 1024.0f;
                H16 c; c.hf = (_Float16)v;
                if (part) { const float rr = v - (float)c.hf; c.hf = (_Float16)rr; }
                h[j] = c.us;
            }
            #pragma unroll
            for (int wj = 0; wj < 4; ++wj)
                wfrag2[i * 4 + wj] = ((unsigned)h[2 * wj + 1] << 16) | h[2 * wj];
        }
    }
}

// ---------------------------------------------------------------------------
// Kernel 1: fused conv1+conv2+fc, one batch per block, 4 blocks/CU.
// LDS (22368 B): lds_in u32[5][392] packed bf16 hi|lo (halo cols zero),
//   h1f fp16[100][72] (rows 0,1,98,99 halo-zero), red f32[32].
// ---------------------------------------------------------------------------
__global__ __launch_bounds__(256, 4) void fused_kernel(
    const float* __restrict__ input,
    const float* __restrict__ b1,
    const float* __restrict__ b2,
    const unsigned* __restrict__ wfrag1,
    const unsigned* __restrict__ wfrag2,
    const float* __restrict__ fc7,
    const float* __restrict__ fc_b,
    const float* __restrict__ taubp,
    float* __restrict__ params)
{
    __shared__ unsigned lds_in[1960];                       // [5][392]
    __shared__ __align__(16) unsigned short h1f[7200];      // [100][72]
    __shared__ float red[32];

    const int t = threadIdx.x, b = blockIdx.x;
    const int lane = t & 63, w = t >> 6;
    const int lq = lane & 31, hi = lane >> 5;

    // ---- zero lds_in + h1 halo rows (0,1,98,99) ----
    for (int i = t; i < 1960; i += 256) lds_in[i] = 0u;
    if (t < 144) {
        const int r = t / 36, wd = t - r * 36;
        const int row = (r < 2) ? r : 96 + r;
        ((unsigned*)h1f)[row * 36 + wd] = 0u;
    }
    __syncthreads();
    const float* inb = input + (size_t)b * 1920;
    for (int i = t; i < 1920; i += 256) {
        const int ic = i / 384, x = i - ic * 384;
        lds_in[ic * 392 + 3 + x] = packsplit(inb[i]);
    }
    __syncthreads();

    // ------------- conv1: C[pos=384][oc=64], K'=48 (3 ks of 16) -------------
    // wave w owns mtiles w*3..w*3+2 (32 pos each), both oc-ntiles.
    // Distance-1 p-buffer across the 9 (m,ks) iterations.
    const i32x4* w1f = (const i32x4*)wfrag1;
    Frag c1b[3][2][2];                       // [ks][nt][part]
    #pragma unroll
    for (int ks = 0; ks < 3; ++ks)
        #pragma unroll
        for (int nt = 0; nt < 2; ++nt) {
            const int fi = ((ks * 2 + nt) * 64 + lane) * 2;
            c1b[ks][nt][0].q = w1f[fi];
            c1b[ks][nt][1].q = w1f[fi + 1];
        }
    float b1v[2];
    #pragma unroll
    for (int nt = 0; nt < 2; ++nt) b1v[nt] = b1[nt * 32 + lq];

    unsigned pbuf[2][8];
    {   // prologue: (m=0, ks=0): ic = hi
        const unsigned* src = lds_in + hi * 392 + (w * 3) * 32 + lq;
        #pragma unroll
        for (int j = 0; j < 8; ++j) pbuf[0][j] = src[j];
    }
    #pragma unroll
    for (int m = 0; m < 3; ++m) {
        const int mtile = w * 3 + m;
        f32x16 acc0 = ZERO16, acc1 = ZERO16;
        #pragma unroll
        for (int ks = 0; ks < 3; ++ks) {
            const int it = m * 3 + ks, cur = it & 1, nxt = cur ^ 1;
            if (it < 8) {
                const int nit = it + 1, nm = nit / 3, nks = nit % 3;
                const int rowoff = (nks == 2) ? 4 * 392 : (nks * 2 + hi) * 392;
                const unsigned* src = lds_in + rowoff + (w * 3 + nm) * 32 + lq;
                #pragma unroll
                for (int j = 0; j < 8; ++j) pbuf[nxt][j] = src[j];
            }
            Frag ah, al;
            #pragma unroll
            for (int wj = 0; wj < 4; ++wj) {
                ah.u[wj] = __builtin_amdgcn_perm(pbuf[cur][2*wj+1], pbuf[cur][2*wj], 0x07060302u);
                al.u[wj] = __builtin_amdgcn_perm(pbuf[cur][2*wj+1], pbuf[cur][2*wj], 0x05040100u);
            }
            if (ks == 2) {     // ic = ks*2+hi = 5 for hi=1: virtual zero row
                #pragma unroll
                for (int wj = 0; wj < 4; ++wj) {
                    ah.u[wj] = hi ? 0 : ah.u[wj];
                    al.u[wj] = hi ? 0 : al.u[wj];
                }
            }
            __builtin_amdgcn_s_setprio(1);
            acc0 = __builtin_amdgcn_mfma_f32_32x32x16_bf16(ah.v, c1b[ks][0][0].v, acc0, 0, 0, 0);
            acc1 = __builtin_amdgcn_mfma_f32_32x32x16_bf16(ah.v, c1b[ks][1][0].v, acc1, 0, 0, 0);
            acc0 = __builtin_amdgcn_mfma_f32_32x32x16_bf16(ah.v, c1b[ks][0][1].v, acc0, 0, 0, 0);
            acc1 = __builtin_amdgcn_mfma_f32_32x32x16_bf16(ah.v, c1b[ks][1][1].v, acc1, 0, 0, 0);
            acc0 = __builtin_amdgcn_mfma_f32_32x32x16_bf16(al.v, c1b[ks][0][0].v, acc0, 0, 0, 0);
            acc1 = __builtin_amdgcn_mfma_f32_32x32x16_bf16(al.v, c1b[ks][1][0].v, acc1, 0, 0, 0);
            __builtin_amdgcn_s_setprio(0);
        }
        // pool4 + relu + single-fp16 write: reg-quad q = rows 8q+4hi+0..3
        #pragma unroll
        for (int q = 0; q < 4; ++q) {
            const int c = mtile * 8 + 2 * q + hi;
            {
                float s = 0.f;
                #pragma unroll
                for (int r4 = 0; r4 < 4; ++r4) s += fmaxf(acc0[q*4+r4] + b1v[0], 0.f);
                h1f[(c + 2) * 72 + lq] = f16_rne(0.25f * s);
            }
            {
                float s = 0.f;
                #pragma unroll
                for (int r4 = 0; r4 < 4; ++r4) s += fmaxf(acc1[q*4+r4] + b1v[1], 0.f);
                h1f[(c + 2) * 72 + 32 + lq] = f16_rne(0.25f * s);
            }
        }
    }
    __syncthreads();

    // ------ conv2: 20 k-steps (dk*4+icc), wave = ntile w, mtiles 0..2 ------
    // A = h1 fp16 single; B = 1024*w2 split fp16.
    // Per-step A-block double-buffer; acc rotation distance 3.
    f32x16 acc2[3] = {ZERO16, ZERO16, ZERO16};

    const i32x4* aF = (const i32x4*)(h1f + lq * 72 + hi * 8);
    const i32x4* w2f = (const i32x4*)wfrag2;
    Frag b2h[2], b2l[2];                     // B double-buffer
    Frag a2f[2][3];                          // per-step A block, dbuf

    {   // prologue: B(step0), A(step0, mt 0..2)
        const int fi = (w * 64 + lane) * 2;
        b2h[0].q = w2f[fi];
        b2l[0].q = w2f[fi + 1];
        #pragma unroll
        for (int mt = 0; mt < 3; ++mt) a2f[0][mt].q = aF[mt * 288];
    }

    #pragma unroll
    for (int s = 0; s < 20; ++s) {
        const int sb = s & 1, nb = sb ^ 1;
        if (s < 19) {
            const int fi = (((s + 1) * 4 + w) * 64 + lane) * 2;
            b2h[nb].q = w2f[fi];
            b2l[nb].q = w2f[fi + 1];
            const int dkn = (s + 1) >> 2, iccn = (s + 1) & 3;
            #pragma unroll
            for (int mt = 0; mt < 3; ++mt)
                a2f[nb][mt].q = aF[(mt * 32 + dkn) * 9 + iccn * 2];
        }
        __builtin_amdgcn_s_setprio(1);
        #pragma unroll
        for (int mt = 0; mt < 3; ++mt)
            acc2[mt] = __builtin_amdgcn_mfma_f32_32x32x16_f16(a2f[sb][mt].h, b2h[sb].h, acc2[mt], 0, 0, 0);
        #pragma unroll
        for (int mt = 0; mt < 3; ++mt)
            acc2[mt] = __builtin_amdgcn_mfma_f32_32x32x16_f16(a2f[sb][mt].h, b2l[sb].h, acc2[mt], 0, 0, 0);
        __builtin_amdgcn_s_setprio(0);
    }

    // ---- epilogue: unscale (2^-10) + bias + relu + pool4 -> feat; fc7T ----
    // fc7T[fq][j][oc]: lane reads oc = w*32+lq -> coalesced dword loads.
    float dot[7] = {0.f, 0.f, 0.f, 0.f, 0.f, 0.f, 0.f};
    {
        const float b2v = b2[w * 32 + lq];
        #pragma unroll
        for (int mt = 0; mt < 3; ++mt) {
            #pragma unroll
            for (int q = 0; q < 4; ++q) {
                float s = 0.f;
                #pragma unroll
                for (int r4 = 0; r4 < 4; ++r4)
                    s += fmaxf(acc2[mt][q*4+r4] * 0.0009765625f + b2v, 0.f);
                s *= 0.25f;
                const int fq = mt * 8 + 2 * q + hi;
                const float* fp = fc7 + fq * 1024 + w * 32 + lq;
                float f[7];
                #pragma unroll
                for (int j = 0; j < 7; ++j) f[j] = fp[j * 128];
                #pragma unroll
                for (int j = 0; j < 7; ++j) dot[j] += s * f[j];
            }
        }
    }

    #pragma unroll
    for (int j = 0; j < 7; ++j) {
        float s = dot[j];
        #pragma unroll
        for (int off = 32; off; off >>= 1) s += __shfl_down(s, off);
        if (lane == 0) red[w * 8 + j] = s;
    }
    __syncthreads();
    if (t < 7) {
        float s = red[t] + red[8 + t] + red[16 + t] + red[24 + t];
        s += (t < 6) ? fc_b[t] : taubp[0];
        params[(size_t)b * 8 + t] = s;
    }
}

// ---------------------------------------------------------------------------
// Kernel 2: DMP rollout — 1 thread per batch element.
// ---------------------------------------------------------------------------
__global__ void rollout_kernel(const float* __restrict__ params,
                               const float* __restrict__ y0,
                               float* __restrict__ out) {
    const int b = blockIdx.x * 256 + threadIdx.x;
    const float* p = params + (size_t)b * 8;
    const float goal = p[0];
    const float w0 = p[1], w1 = p[2], w2 = p[3], w3 = p[4], w4 = p[5];
    const float tau = p[6];
    const float y0v = y0[b];

    const float c0 = 1.0f;
    const float c1 = 0.77880078307140486825f;
    const float c2 = 0.60653065971263342360f;
    const float c3 = 0.47236655274101470714f;
    const float c4 = 0.36787944117144232160f;
    const float inv2s = -0.5f / 11.180339887498949f;
    const float e0 = inv2s * c0, e1 = inv2s * c1, e2 = inv2s * c2,
                e3 = inv2s * c3, e4 = inv2s * c4;

    float x = 1.0f, y = y0v, z = 0.01f * tau;
    const float td = tau * 0.01f;
    const float gmy0 = goal - y0v;
    float* ob = out + (size_t)b * 101;
    ob[0] = y0v;
    for (int s = 1; s <= 100; ++s) {
        x = x - x * td;
        const float d0 = x - c0, d1 = x - c1, d2 = x - c2, d3 = x - c3, d4 = x - c4;
        const float p0 = __expf(e0 * d0 * d0);
        const float p1 = __expf(e1 * d1 * d1);
        const float p2 = __expf(e2 * d2 * d2);
        const float p3 = __expf(e3 * d3 * d3);
        const float p4 = __expf(e4 * d4 * d4);
        const float den = p0 + p1 + p2 + p3 + p4;
        const float num = w0 * p0 + w1 * p1 + w2 * p2 + w3 * p3 + w4 * p4;
        const float fx = (num / den) * x * gmy0;
        const float dz = 25.0f * (6.25f * (goal - y) - z) + fx;
        const float dy = z;
        y += dy * td;
        z += dz * td;
        ob[s] = y;
    }
}

extern "C" void kernel_launch(void* const* d_in, const int* in_sizes, int n_in,
                              void* d_out, int out_size, void* d_ws, size_t ws_size,
                              hipStream_t stream) {
    const float* input = (const float*)d_in[0];
    const float* y0    = (const float*)d_in[1];
    const float* w1    = (const float*)d_in[2];
    const float* b1    = (const float*)d_in[3];
    const float* w2    = (const float*)d_in[4];
    const float* b2    = (const float*)d_in[5];
    const float* fc_w  = (const float*)d_in[6];
    const float* fc_b  = (const float*)d_in[7];
    const float* L_w   = (const float*)d_in[8];
    const float* L_b   = (const float*)d_in[9];
    float* out = (float*)d_out;

    float* ws      = (float*)d_ws;
    float* fc7     = ws;                          // 24576 f (fc7T layout)
    float* taub    = ws + 24576;                  // pad to 64
    float* params  = ws + 24640;                  // 32768 f
    unsigned* wfrag1 = (unsigned*)(ws + 57408);   // 3072 u32 (pad to 4096)
    unsigned* wfrag2 = wfrag1 + 4096;             // 40960 u32

    const int B = in_sizes[1];                    // 4096

    precompute_kernel<<<69, 256, 0, stream>>>(w1, w2, fc_w, fc_b, L_w, L_b,
                                              fc7, taub, wfrag1, wfrag2);
    fused_kernel<<<B, 256, 0, stream>>>(input, b1, b2, wfrag1, wfrag2,
                                        fc7, fc_b, taub, params);
    rollout_kernel<<<B / 256, 256, 0, stream>>>(params, y0, out);
}

// Round 13
// 92.529 us; speedup vs baseline: 4.9910x; 1.4352x over previous
//
#include <hip/hip_runtime.h>
#include <math.h>

// ---------------------------------------------------------------------------
// B=4096. conv1 (64,5,7) pad3 + relu + pool4 -> h1 (64,96)
//         conv2 (128,64,5) pad2 + relu + pool4 -> feat (128,24)
//         fc: only cols 0..5 of (404,3072) + tau = feat·(L_w@fc_w) + const.
// Precision (R13): conv1 = 2-term fp16 (A = f16(input), B = 1024*w1 split
// hi/lo -> err ~2^-11); conv2 = 1-term fp16 (A = f16(h1), B = f16(1024*w2)
// -> err ~2^-10). Epilogues unscale 2^-10. Error model from measured
// points (2^-16 -> 16, conv2-A-only 2^-11 -> 64) predicts absmax ~150-340
// vs threshold 460.8. MFMA/wave: 174 -> 96 (floor 37.5 -> 21 us).
// Both convs on v_mfma_f32_32x32x16_f16.
// C/D (m74/m101): col=lane&31(oc), row=(reg&3)+8*(reg>>2)+4*(lane>>5) ->
// reg-quads = 4 consecutive pos -> pool4 in-register.
// R9 lesson: launch_bounds stays (256,4) — conv1 peak ~119 regs.
// ---------------------------------------------------------------------------

typedef short bf16x8 __attribute__((ext_vector_type(8)));
typedef _Float16 f16x8 __attribute__((ext_vector_type(8)));
typedef float f32x4  __attribute__((ext_vector_type(4)));
typedef float f32x16 __attribute__((ext_vector_type(16)));
typedef int   i32x4  __attribute__((ext_vector_type(4)));

union Frag { int u[4]; i32x4 q; bf16x8 v; f16x8 h; };
union H16 { _Float16 hf; unsigned short us; };

__device__ __forceinline__ unsigned short f16_rne(float f) {
    H16 c; c.hf = (_Float16)f; return c.us;
}

#define ZERO16 {0.f,0.f,0.f,0.f,0.f,0.f,0.f,0.f,0.f,0.f,0.f,0.f,0.f,0.f,0.f,0.f}

// ---------------------------------------------------------------------------
// Kernel 0 (512 thr): fc7T (blocks 0..47), taub+wfrag1 (48), wfrag2 (49..58).
//  fc7T: [fq24][j8][oc128] f32; j0..5 = fc_w cols, j6 = L_w@fc_w, j7 = 0
//  wfrag1: [ks3][nt2][lane64][part2][4u32] f16 split of 1024*w1;
//          k'=ks*16+(lane>>5)*8+j -> ic=k'>>3, dk=k'&7 (ic==5 -> zero)
//  wfrag2: [step20][nt4][lane64][4u32] f16 of 1024*w2; step=dk*4+icc;
//          k_ic=icc*16+(lane>>5)*8+j
// ---------------------------------------------------------------------------
__global__ void precompute_kernel(const float* __restrict__ w1,
                                  const float* __restrict__ w2,
                                  const float* __restrict__ fc_w,
                                  const float* __restrict__ fc_b,
                                  const float* __restrict__ L_w,
                                  const float* __restrict__ L_b,
                                  float* __restrict__ fc7,
                                  float* __restrict__ taub,
                                  unsigned* __restrict__ wfrag1,
                                  unsigned* __restrict__ wfrag2) {
    const int t = threadIdx.x, bb = blockIdx.x;
    if (bb < 48) {
        __shared__ float part[7][64];
        const int k = bb * 64 + (t & 63), jc = t >> 6;       // jc 0..7
        const int j0 = jc * 51;
        float s = 0.f;
        #pragma unroll 8
        for (int j = j0; j < j0 + 51 && j < 404; ++j)
            s += L_w[j] * fc_w[j * 3072 + k];
        if (jc) part[jc - 1][t & 63] = s;
        __syncthreads();
        if (jc == 0) {
            const int kk = t & 63;
            const int oc = k / 24, fq = k - oc * 24;
            float r[8];
            #pragma unroll
            for (int j = 0; j < 6; ++j) r[j] = fc_w[j * 3072 + k];
            float tv = s;
            #pragma unroll
            for (int j = 0; j < 7; ++j) tv += part[j][kk];
            r[6] = tv; r[7] = 0.f;
            #pragma unroll
            for (int j = 0; j < 8; ++j) fc7[fq * 1024 + j * 128 + oc] = r[j];
        }
    } else if (bb == 48) {
        if (t < 64) {
            float s = 0.f;
            for (int j = t; j < 404; j += 64) s += L_w[j] * fc_b[j];
            #pragma unroll
            for (int off = 32; off; off >>= 1) s += __shfl_down(s, off);
            if (t == 0) taub[0] = s + L_b[0];
        }
        for (int i = t; i < 768; i += 512) {        // conv1 frags (f16 split)
            const int part = i & 1, lane = (i >> 1) & 63,
                      nt = (i >> 7) & 1, ks = i >> 8;        // 0..2
            const int oc = nt * 32 + (lane & 31);
            unsigned short h[8];
            #pragma unroll
            for (int j = 0; j < 8; ++j) {
                const int kp = ks * 16 + (lane >> 5) * 8 + j;  // k' = ic*8+dk
                const int ic = kp >> 3, dk = kp & 7;
                const float v = (ic < 5 && dk < 7)
                              ? w1[oc * 35 + ic * 7 + dk] * 1024.0f : 0.f;
                H16 c; c.hf = (_Float16)v;
                if (part) { const float rr = v - (float)c.hf; c.hf = (_Float16)rr; }
                h[j] = c.us;
            }
            #pragma unroll
            for (int wj = 0; wj < 4; ++wj)
                wfrag1[i * 4 + wj] = ((unsigned)h[2 * wj + 1] << 16) | h[2 * wj];
        }
    } else {                                        // conv2 frags: 5120 items
        const int i = (bb - 49) * 512 + t;
        const int lane = i & 63, nt = (i >> 6) & 3, step = i >> 8;   // 0..19
        const int oc = nt * 32 + (lane & 31);
        const int dk = step >> 2, icc = step & 3;
        unsigned short h[8];
        #pragma unroll
        for (int j = 0; j < 8; ++j) {
            const int ic = icc * 16 + (lane >> 5) * 8 + j;  // k = ic
            const float v = w2[oc * 320 + ic * 5 + dk] * 1024.0f;
            h[j] = f16_rne(v);
        }
        #pragma unroll
        for (int wj = 0; wj < 4; ++wj)
            wfrag2[i * 4 + wj] = ((unsigned)h[2 * wj + 1] << 16) | h[2 * wj];
    }
}

// ---------------------------------------------------------------------------
// Kernel 1: fused conv1+conv2+fc, one batch per block, 4 blocks/CU.
// LDS (22368 B): lds_in u32[5][392] = zero-extended f16(input) (halo zero),
//   h1f fp16[100][72] (rows 0,1,98,99 halo-zero), red f32[32].
// ---------------------------------------------------------------------------
__global__ __launch_bounds__(256, 4) void fused_kernel(
    const float* __restrict__ input,
    const float* __restrict__ b1,
    const float* __restrict__ b2,
    const unsigned* __restrict__ wfrag1,
    const unsigned* __restrict__ wfrag2,
    const float* __restrict__ fc7,
    const float* __restrict__ fc_b,
    const float* __restrict__ taubp,
    float* __restrict__ params)
{
    __shared__ unsigned lds_in[1960];                       // [5][392]
    __shared__ __align__(16) unsigned short h1f[7200];      // [100][72]
    __shared__ float red[32];

    const int t = threadIdx.x, b = blockIdx.x;
    const int lane = t & 63, w = t >> 6;
    const int lq = lane & 31, hi = lane >> 5;

    // ---- zero lds_in + h1 halo rows (0,1,98,99) ----
    for (int i = t; i < 1960; i += 256) lds_in[i] = 0u;
    if (t < 144) {
        const int r = t / 36, wd = t - r * 36;
        const int row = (r < 2) ? r : 96 + r;
        ((unsigned*)h1f)[row * 36 + wd] = 0u;
    }
    __syncthreads();
    const float* inb = input + (size_t)b * 1920;
    for (int i = t; i < 1920; i += 256) {
        const int ic = i / 384, x = i - ic * 384;
        lds_in[ic * 392 + 3 + x] = (unsigned)f16_rne(inb[i]);
    }
    __syncthreads();

    // ------------- conv1: C[pos=384][oc=64], K'=48 (3 ks of 16) -------------
    // A single f16 (low half of u32, gathered by one perm per pair);
    // B = 1024*w1 split hi/lo -> 4 MFMA per (m,ks). Distance-1 p-buffer.
    const i32x4* w1f = (const i32x4*)wfrag1;
    Frag c1b[3][2][2];                       // [ks][nt][part]
    #pragma unroll
    for (int ks = 0; ks < 3; ++ks)
        #pragma unroll
        for (int nt = 0; nt < 2; ++nt) {
            const int fi = ((ks * 2 + nt) * 64 + lane) * 2;
            c1b[ks][nt][0].q = w1f[fi];
            c1b[ks][nt][1].q = w1f[fi + 1];
        }
    float b1v[2];
    #pragma unroll
    for (int nt = 0; nt < 2; ++nt) b1v[nt] = b1[nt * 32 + lq];

    unsigned pbuf[2][8];
    {   // prologue: (m=0, ks=0): ic = hi
        const unsigned* src = lds_in + hi * 392 + (w * 3) * 32 + lq;
        #pragma unroll
        for (int j = 0; j < 8; ++j) pbuf[0][j] = src[j];
    }
    #pragma unroll
    for (int m = 0; m < 3; ++m) {
        const int mtile = w * 3 + m;
        f32x16 acc0 = ZERO16, acc1 = ZERO16;
        #pragma unroll
        for (int ks = 0; ks < 3; ++ks) {
            const int it = m * 3 + ks, cur = it & 1, nxt = cur ^ 1;
            if (it < 8) {
                const int nit = it + 1, nm = nit / 3, nks = nit % 3;
                const int rowoff = (nks == 2) ? 4 * 392 : (nks * 2 + hi) * 392;
                const unsigned* src = lds_in + rowoff + (w * 3 + nm) * 32 + lq;
                #pragma unroll
                for (int j = 0; j < 8; ++j) pbuf[nxt][j] = src[j];
            }
            Frag af;
            #pragma unroll
            for (int wj = 0; wj < 4; ++wj)
                af.u[wj] = __builtin_amdgcn_perm(pbuf[cur][2*wj+1], pbuf[cur][2*wj], 0x05040100u);
            if (ks == 2) {     // ic = ks*2+hi = 5 for hi=1: virtual zero row
                #pragma unroll
                for (int wj = 0; wj < 4; ++wj) af.u[wj] = hi ? 0 : af.u[wj];
            }
            __builtin_amdgcn_s_setprio(1);
            acc0 = __builtin_amdgcn_mfma_f32_32x32x16_f16(af.h, c1b[ks][0][0].h, acc0, 0, 0, 0);
            acc1 = __builtin_amdgcn_mfma_f32_32x32x16_f16(af.h, c1b[ks][1][0].h, acc1, 0, 0, 0);
            acc0 = __builtin_amdgcn_mfma_f32_32x32x16_f16(af.h, c1b[ks][0][1].h, acc0, 0, 0, 0);
            acc1 = __builtin_amdgcn_mfma_f32_32x32x16_f16(af.h, c1b[ks][1][1].h, acc1, 0, 0, 0);
            __builtin_amdgcn_s_setprio(0);
        }
        // unscale 2^-10 + bias + relu + pool4 -> f16 write
        #pragma unroll
        for (int q = 0; q < 4; ++q) {
            const int c = mtile * 8 + 2 * q + hi;
            {
                float s = 0.f;
                #pragma unroll
                for (int r4 = 0; r4 < 4; ++r4)
                    s += fmaxf(acc0[q*4+r4] * 0.0009765625f + b1v[0], 0.f);
                h1f[(c + 2) * 72 + lq] = f16_rne(0.25f * s);
            }
            {
                float s = 0.f;
                #pragma unroll
                for (int r4 = 0; r4 < 4; ++r4)
                    s += fmaxf(acc1[q*4+r4] * 0.0009765625f + b1v[1], 0.f);
                h1f[(c + 2) * 72 + 32 + lq] = f16_rne(0.25f * s);
            }
        }
    }
    __syncthreads();

    // ------ conv2: 20 k-steps (dk*4+icc), wave = ntile w, mtiles 0..2 ------
    // A = f16(h1); B = f16(1024*w2) single -> 1 MFMA per (s,mt), acc
    // rotation distance 3. Per-step A-block + B double-buffer.
    f32x16 acc2[3] = {ZERO16, ZERO16, ZERO16};

    const i32x4* aF = (const i32x4*)(h1f + lq * 72 + hi * 8);
    const i32x4* w2f = (const i32x4*)wfrag2;
    Frag b2b[2];                             // B double-buffer
    Frag a2f[2][3];                          // per-step A block, dbuf

    {   // prologue: B(step0), A(step0, mt 0..2)
        b2b[0].q = w2f[w * 64 + lane];
        #pragma unroll
        for (int mt = 0; mt < 3; ++mt) a2f[0][mt].q = aF[mt * 288];
    }

    #pragma unroll
    for (int s = 0; s < 20; ++s) {
        const int sb = s & 1, nb = sb ^ 1;
        if (s < 19) {
            b2b[nb].q = w2f[((s + 1) * 4 + w) * 64 + lane];
            const int dkn = (s + 1) >> 2, iccn = (s + 1) & 3;
            #pragma unroll
            for (int mt = 0; mt < 3; ++mt)
                a2f[nb][mt].q = aF[(mt * 32 + dkn) * 9 + iccn * 2];
        }
        __builtin_amdgcn_s_setprio(1);
        #pragma unroll
        for (int mt = 0; mt < 3; ++mt)
            acc2[mt] = __builtin_amdgcn_mfma_f32_32x32x16_f16(a2f[sb][mt].h, b2b[sb].h, acc2[mt], 0, 0, 0);
        __builtin_amdgcn_s_setprio(0);
    }

    // ---- epilogue: unscale (2^-10) + bias + relu + pool4 -> feat; fc7T ----
    float dot[7] = {0.f, 0.f, 0.f, 0.f, 0.f, 0.f, 0.f};
    {
        const float b2v = b2[w * 32 + lq];
        #pragma unroll
        for (int mt = 0; mt < 3; ++mt) {
            #pragma unroll
            for (int q = 0; q < 4; ++q) {
                float s = 0.f;
                #pragma unroll
                for (int r4 = 0; r4 < 4; ++r4)
                    s += fmaxf(acc2[mt][q*4+r4] * 0.0009765625f + b2v, 0.f);
                s *= 0.25f;
                const int fq = mt * 8 + 2 * q + hi;
                const float* fp = fc7 + fq * 1024 + w * 32 + lq;
                float f[7];
                #pragma unroll
                for (int j = 0; j < 7; ++j) f[j] = fp[j * 128];
                #pragma unroll
                for (int j = 0; j < 7; ++j) dot[j] += s * f[j];
            }
        }
    }

    #pragma unroll
    for (int j = 0; j < 7; ++j) {
        float s = dot[j];
        #pragma unroll
        for (int off = 32; off; off >>= 1) s += __shfl_down(s, off);
        if (lane == 0) red[w * 8 + j] = s;
    }
    __syncthreads();
    if (t < 7) {
        float s = red[t] + red[8 + t] + red[16 + t] + red[24 + t];
        s += (t < 6) ? fc_b[t] : taubp[0];
        params[(size_t)b * 8 + t] = s;
    }
}

// ---------------------------------------------------------------------------
// Kernel 2: DMP rollout — 1 thread per batch element.
// ---------------------------------------------------------------------------
__global__ void rollout_kernel(const float* __restrict__ params,
                               const float* __restrict__ y0,
                               float* __restrict__ out) {
    const int b = blockIdx.x * 256 + threadIdx.x;
    const float* p = params + (size_t)b * 8;
    const float goal = p[0];
    const float w0 = p[1], w1 = p[2], w2 = p[3], w3 = p[4], w4 = p[5];
    const float tau = p[6];
    const float y0v = y0[b];

    const float c0 = 1.0f;
    const float c1 = 0.77880078307140486825f;
    const float c2 = 0.60653065971263342360f;
    const float c3 = 0.47236655274101470714f;
    const float c4 = 0.36787944117144232160f;
    const float inv2s = -0.5f / 11.180339887498949f;
    const float e0 = inv2s * c0, e1 = inv2s * c1, e2 = inv2s * c2,
                e3 = inv2s * c3, e4 = inv2s * c4;

    float x = 1.0f, y = y0v, z = 0.01f * tau;
    const float td = tau * 0.01f;
    const float gmy0 = goal - y0v;
    float* ob = out + (size_t)b * 101;
    ob[0] = y0v;
    for (int s = 1; s <= 100; ++s) {
        x = x - x * td;
        const float d0 = x - c0, d1 = x - c1, d2 = x - c2, d3 = x - c3, d4 = x - c4;
        const float p0 = __expf(e0 * d0 * d0);
        const float p1 = __expf(e1 * d1 * d1);
        const float p2 = __expf(e2 * d2 * d2);
        const float p3 = __expf(e3 * d3 * d3);
        const float p4 = __expf(e4 * d4 * d4);
        const float den = p0 + p1 + p2 + p3 + p4;
        const float num = w0 * p0 + w1 * p1 + w2 * p2 + w3 * p3 + w4 * p4;
        const float fx = (num / den) * x * gmy0;
        const float dz = 25.0f * (6.25f * (goal - y) - z) + fx;
        const float dy = z;
        y += dy * td;
        z += dz * td;
        ob[s] = y;
    }
}

extern "C" void kernel_launch(void* const* d_in, const int* in_sizes, int n_in,
                              void* d_out, int out_size, void* d_ws, size_t ws_size,
                              hipStream_t stream) {
    const float* input = (const float*)d_in[0];
    const float* y0    = (const float*)d_in[1];
    const float* w1    = (const float*)d_in[2];
    const float* b1    = (const float*)d_in[3];
    const float* w2    = (const float*)d_in[4];
    const float* b2    = (const float*)d_in[5];
    const float* fc_w  = (const float*)d_in[6];
    const float* fc_b  = (const float*)d_in[7];
    const float* L_w   = (const float*)d_in[8];
    const float* L_b   = (const float*)d_in[9];
    float* out = (float*)d_out;

    float* ws      = (float*)d_ws;
    float* fc7     = ws;                          // 24576 f (fc7T layout)
    float* taub    = ws + 24576;                  // pad to 64
    float* params  = ws + 24640;                  // 32768 f
    unsigned* wfrag1 = (unsigned*)(ws + 57408);   // 3072 u32 (pad to 4096)
    unsigned* wfrag2 = wfrag1 + 4096;             // 20480 u32

    const int B = in_sizes[1];                    // 4096

    precompute_kernel<<<59, 512, 0, stream>>>(w1, w2, fc_w, fc_b, L_w, L_b,
                                              fc7, taub, wfrag1, wfrag2);
    fused_kernel<<<B, 256, 0, stream>>>(input, b1, b2, wfrag1, wfrag2,
                                        fc7, fc_b, taub, params);
    rollout_kernel<<<B / 256, 256, 0, stream>>>(params, y0, out);
}